// Round 2
// baseline (523.623 us; speedup 1.0000x reference)
//
#include <hip/hip_runtime.h>
#include <hip/hip_bf16.h>
#include <cstdint>
#include <cmath>

#define BB 1024
#define CC 256
#define SS 64
#define DD 128
#define TOPKN 8
#define EPSF 1e-8f

// ---------------- kernel 0: n_emb[b] = ||emb[b]|| ----------------
__global__ __launch_bounds__(256) void nemb_kernel(const float* __restrict__ emb,
                                                   float* __restrict__ nemb) {
    int b = blockIdx.x * 4 + (threadIdx.x >> 6);
    int l = threadIdx.x & 63;
    const float* e = emb + (size_t)b * DD;
    float x0 = e[l], x1 = e[64 + l];
    float s = x0 * x0 + x1 * x1;
    #pragma unroll
    for (int off = 32; off; off >>= 1) s += __shfl_down(s, off);
    if (l == 0) nemb[b] = sqrtf(s);
}

// ------- kernel 1: Gram G[c] = W[c] W[c]^T  (64x64), nw = sqrt(diag) -------
__global__ __launch_bounds__(256) void gram_kernel(const float* __restrict__ weight,
                                                   float* __restrict__ G,
                                                   float* __restrict__ nw_g) {
    __shared__ float Wc[SS][DD + 4];   // +4 pad: row stride 132 words breaks bank aliasing
    int c = blockIdx.x;
    const float4* wsrc = (const float4*)(weight + (size_t)c * SS * DD);
    for (int i = threadIdx.x; i < SS * DD / 4; i += 256) {
        int s = i >> 5, d4 = i & 31;            // 32 float4 per row
        *(float4*)&Wc[s][d4 << 2] = wsrc[i];
    }
    __syncthreads();
    int ti = threadIdx.x >> 4, tj = threadIdx.x & 15;   // 16x16 grid of 4x4 tiles
    float acc[4][4] = {};
    for (int d = 0; d < DD; d += 4) {
        float4 a[4], bv[4];
        #pragma unroll
        for (int r = 0; r < 4; r++) a[r] = *(const float4*)&Wc[4 * ti + r][d];
        #pragma unroll
        for (int r = 0; r < 4; r++) bv[r] = *(const float4*)&Wc[4 * tj + r][d];
        #pragma unroll
        for (int r = 0; r < 4; r++)
            #pragma unroll
            for (int q = 0; q < 4; q++)
                acc[r][q] += a[r].x * bv[q].x + a[r].y * bv[q].y +
                             a[r].z * bv[q].z + a[r].w * bv[q].w;
    }
    float* Gc = G + (size_t)c * SS * SS;
    #pragma unroll
    for (int r = 0; r < 4; r++)
        #pragma unroll
        for (int q = 0; q < 4; q++) {
            int s1 = 4 * ti + r, s2 = 4 * tj + q;
            Gc[s1 * SS + s2] = acc[r][q];
            if (s1 == s2) nw_g[c * SS + s1] = sqrtf(acc[r][q]);
        }
}

// ---------------- kernel 2: dot tile + top8 + softmax + epilogue ----------------
// block = (c, group of 64 b).  4 waves; lane <-> b; wave w covers s in [16w,16w+16).
// emb row (128 fp32) lives in VGPRs; weight rows broadcast from cache.
__global__ __launch_bounds__(256) void main_kernel(const float* __restrict__ emb,
                                                   const float* __restrict__ weight,
                                                   const float* __restrict__ G,
                                                   const float* __restrict__ nw_g,
                                                   const float* __restrict__ nemb,
                                                   float* __restrict__ out) {
    __shared__ float dotL[SS][SS + 2];   // stride 66: 2-way bank alias = free
    __shared__ float nwL[SS];
    int c = blockIdx.x, b0 = blockIdx.y * 64;
    int lane = threadIdx.x & 63, w = threadIdx.x >> 6;

    if (threadIdx.x < SS) nwL[threadIdx.x] = nw_g[c * SS + threadIdx.x];

    // stage emb[b0+lane][:] into registers (32 float4 = 128 VGPRs)
    const float4* ep = (const float4*)(emb + (size_t)(b0 + lane) * DD);
    float4 e[32];
    #pragma unroll
    for (int i = 0; i < 32; i++) e[i] = ep[i];

    const float* wp = weight + ((size_t)c * SS + (size_t)w * 16) * DD;
    for (int si = 0; si < 16; si++) {
        const float4* wrow = (const float4*)(wp + si * DD);  // uniform across wave
        float a0 = 0.f, a1 = 0.f, a2 = 0.f, a3 = 0.f;        // 4 chains hide FMA latency
        #pragma unroll
        for (int i = 0; i < 32; i++) {
            float4 wv = wrow[i];
            a0 = fmaf(e[i].x, wv.x, a0);
            a1 = fmaf(e[i].y, wv.y, a1);
            a2 = fmaf(e[i].z, wv.z, a2);
            a3 = fmaf(e[i].w, wv.w, a3);
        }
        dotL[lane][w * 16 + si] = (a0 + a1) + (a2 + a3);
    }
    __syncthreads();

    if (threadIdx.x < SS) {
        int bl = threadIdx.x;
        float ne = nemb[b0 + bl];

        // exact-fp32 top-8: strict '>' insertion network; iterate s ascending so
        // equal scores keep the LOWER index ranked higher (lax.top_k semantics)
        float ts[TOPKN]; int ti[TOPKN];
        #pragma unroll
        for (int k = 0; k < TOPKN; k++) { ts[k] = -INFINITY; ti[k] = 0; }
        for (int s = 0; s < SS; s++) {
            float denom = fmaxf(ne * nwL[s], EPSF);
            float cosv = dotL[bl][s] / denom;              // IEEE div, matches ref
            float xs = (1.0f + cosv) * 0.5f + EPSF;        // literal ref expression
            int xi = s;
            #pragma unroll
            for (int k = 0; k < TOPKN; k++) {
                bool gt = xs > ts[k];
                float hs = gt ? xs : ts[k];  int hi = gt ? xi : ti[k];
                float ls = gt ? ts[k] : xs;  int li = gt ? ti[k] : xi;
                ts[k] = hs; ti[k] = hi; xs = ls; xi = li;
            }
        }
        // softmax over the 8 (ts[0] is the max since sorted desc)
        float wk[TOPKN];
        float wsum = 0.f;
        #pragma unroll
        for (int k = 0; k < TOPKN; k++) {
            float ev = expf(ts[k] - ts[0]);
            wk[k] = ev; wsum += ev;
        }
        float winv = 1.0f / wsum;

        // dot2 = sum_k w_k dot[idx_k]   (bilinearity: protos never materialized)
        float dot2 = 0.f;
        #pragma unroll
        for (int k = 0; k < TOPKN; k++) dot2 += wk[k] * dotL[bl][ti[k]];

        // ||proto||^2 = sum_{j,k} w_j w_k G[idx_j][idx_k]  (symmetry: 36 gathers)
        const float* Gc = G + (size_t)c * SS * SS;
        float np2 = 0.f;
        #pragma unroll
        for (int j = 0; j < TOPKN; j++) {
            float wj = wk[j];
            np2 += wj * wj * Gc[ti[j] * SS + ti[j]];
            #pragma unroll
            for (int k2 = j + 1; k2 < TOPKN; k2++)
                np2 += 2.0f * wj * wk[k2] * Gc[ti[j] * SS + ti[k2]];
        }
        dot2 *= winv;
        np2 *= winv * winv;

        float denom2 = fmaxf(sqrtf(fmaxf(np2, 0.f)) * ne, EPSF);
        float cos2 = dot2 / denom2;
        // ((1+cos2)/2 + eps) / 0.1  — literal division to match ref rounding
        out[(size_t)(b0 + bl) * CC + c] = ((1.0f + cos2) * 0.5f + EPSF) / 0.1f;
    }
}

extern "C" void kernel_launch(void* const* d_in, const int* in_sizes, int n_in,
                              void* d_out, int out_size, void* d_ws, size_t ws_size,
                              hipStream_t stream) {
    const float* emb    = (const float*)d_in[0];
    const float* weight = (const float*)d_in[1];
    float* G    = (float*)d_ws;                       // 256*64*64 = 4 MB
    float* nw   = G + (size_t)CC * SS * SS;           // 64 KB
    float* nemb = nw + (size_t)CC * SS;               // 4 KB
    float* out  = (float*)d_out;

    hipLaunchKernelGGL(nemb_kernel, dim3(BB / 4), dim3(256), 0, stream, emb, nemb);
    hipLaunchKernelGGL(gram_kernel, dim3(CC), dim3(256), 0, stream, weight, G, nw);
    hipLaunchKernelGGL(main_kernel, dim3(CC, BB / 64), dim3(256), 0, stream,
                       emb, weight, G, nw, nemb, out);
}